// Round 1
// baseline (304.692 us; speedup 1.0000x reference)
//
#include <hip/hip_runtime.h>

// ProtoNet forward: per (b,p) pair 16x64 sinkhorn (30 it, eps=0.1) + FFN head.
// Layout: one wave per pair. lane = ig*16 + jg (ig=0..3, jg=0..15).
// Lane owns rows i = ig + 4r (r=0..3) and cols j = jg + 16t (t=0..3).
// All sinkhorn state in registers, base-2 log domain.

constexpr int   LMAX_ = 64, D_ = 128, PCS_ = 16;
constexpr float EPS_   = 0.1f;
constexpr float LOG2E_ = 1.4426950408889634f;
constexpr float SCALE_ = LOG2E_ / EPS_;          // C -> base-2/eps units
constexpr float LN2_   = 0.6931471805599453f;
constexpr int   NIT_   = 30;
constexpr int   LDSW_  = 132;                    // odd*4 stride: 2-way-only LDS conflicts

#if __has_builtin(__builtin_amdgcn_exp2f)
__device__ __forceinline__ float exp2_(float x) { return __builtin_amdgcn_exp2f(x); }
#else
__device__ __forceinline__ float exp2_(float x) { return exp2f(x); }
#endif
#if __has_builtin(__builtin_amdgcn_log2f)
__device__ __forceinline__ float log2_(float x) { return __builtin_amdgcn_log2f(x); }
#elif __has_builtin(__builtin_amdgcn_logf)
__device__ __forceinline__ float log2_(float x) { return __builtin_amdgcn_logf(x); }  // v_log_f32 = log2
#else
__device__ __forceinline__ float log2_(float x) { return log2f(x); }
#endif

__global__ __launch_bounds__(256, 4) void sink_fused(
    const float* __restrict__ atom_h,   // [512][64][128]
    const float* __restrict__ pc_X,     // [32][16][128]
    const int*   __restrict__ n_atoms,  // [512]
    float*       __restrict__ mol)      // [512][32] (ws)
{
  __shared__ float Alds[64 * LDSW_];

  const int b    = blockIdx.x >> 3;                 // 8 blocks per molecule
  const int wave = threadIdx.x >> 6;
  const int pair = blockIdx.x * 4 + wave;           // = b*32 + p
  const int p    = pair & 31;
  const int lane = threadIdx.x & 63;
  const int ig   = lane >> 4;
  const int jg   = lane & 15;

  // ---- stage atom_h[b] into LDS (coalesced), padded stride ----
  const float* Ag = atom_h + (size_t)b * (LMAX_ * D_);
  #pragma unroll
  for (int u = 0; u < 8; ++u) {
    int fidx = u * 256 + threadIdx.x;               // float4 index, 2048 total
    int row  = fidx >> 5;
    int c4   = fidx & 31;
    float4 v = *reinterpret_cast<const float4*>(Ag + row * D_ + c4 * 4);
    *reinterpret_cast<float4*>(&Alds[row * LDSW_ + c4 * 4]) = v;
  }
  __syncthreads();

  const int    n  = n_atoms[b];
  const float* Xg = pc_X + (size_t)p * (PCS_ * D_);

  // ---- cost tile: Cb[r][t] = SCALE * (||x_i||^2 + ||a_j||^2 - 2 x_i.a_j) ----
  float acc[4][4], an[4], pn[4];
  #pragma unroll
  for (int r = 0; r < 4; ++r) { pn[r] = 0.f;
    #pragma unroll
    for (int t = 0; t < 4; ++t) acc[r][t] = 0.f; }
  #pragma unroll
  for (int t = 0; t < 4; ++t) an[t] = 0.f;

  for (int c = 0; c < 32; ++c) {
    float4 at[4], px[4];
    #pragma unroll
    for (int t = 0; t < 4; ++t)
      at[t] = *reinterpret_cast<const float4*>(&Alds[(jg + 16 * t) * LDSW_ + c * 4]);
    #pragma unroll
    for (int r = 0; r < 4; ++r)
      px[r] = *reinterpret_cast<const float4*>(Xg + (ig + 4 * r) * D_ + c * 4);
    #pragma unroll
    for (int r = 0; r < 4; ++r)
      #pragma unroll
      for (int t = 0; t < 4; ++t) {
        acc[r][t] = fmaf(px[r].x, at[t].x, acc[r][t]);
        acc[r][t] = fmaf(px[r].y, at[t].y, acc[r][t]);
        acc[r][t] = fmaf(px[r].z, at[t].z, acc[r][t]);
        acc[r][t] = fmaf(px[r].w, at[t].w, acc[r][t]);
      }
    #pragma unroll
    for (int t = 0; t < 4; ++t) {
      an[t] = fmaf(at[t].x, at[t].x, an[t]); an[t] = fmaf(at[t].y, at[t].y, an[t]);
      an[t] = fmaf(at[t].z, at[t].z, an[t]); an[t] = fmaf(at[t].w, at[t].w, an[t]);
    }
    #pragma unroll
    for (int r = 0; r < 4; ++r) {
      pn[r] = fmaf(px[r].x, px[r].x, pn[r]); pn[r] = fmaf(px[r].y, px[r].y, pn[r]);
      pn[r] = fmaf(px[r].z, px[r].z, pn[r]); pn[r] = fmaf(px[r].w, px[r].w, pn[r]);
    }
  }

  float Cb[4][4];
  #pragma unroll
  for (int r = 0; r < 4; ++r)
    #pragma unroll
    for (int t = 0; t < 4; ++t)
      Cb[r][t] = fmaf(-2.0f, acc[r][t], pn[r] + an[t]) * SCALE_;

  // ---- sinkhorn state (base-2 units) ----
  float lb2[4], G[4], F[4];
  const float lbv = -log2_((float)n);
  #pragma unroll
  for (int t = 0; t < 4; ++t) {
    const int j = jg + 16 * t;
    lb2[t] = (j < n) ? lbv : -1.4426950e9f;  // log2e * NEG
    G[t]   = (j < n) ? 0.0f : -1e9f;         // padded cols contribute exactly 0 from it 1
  }

  for (int it = 0; it < NIT_; ++it) {
    // f update: F_i = -4 - lse2_j(G_j - Cb_ij); reduce over t (local) + jg (xor 1..8)
    #pragma unroll
    for (int r = 0; r < 4; ++r) {
      float x0 = G[0] - Cb[r][0], x1 = G[1] - Cb[r][1];
      float x2 = G[2] - Cb[r][2], x3 = G[3] - Cb[r][3];
      float m = fmaxf(fmaxf(x0, x1), fmaxf(x2, x3));
      m = fmaxf(m, __shfl_xor(m, 1));
      m = fmaxf(m, __shfl_xor(m, 2));
      m = fmaxf(m, __shfl_xor(m, 4));
      m = fmaxf(m, __shfl_xor(m, 8));
      float s = exp2_(x0 - m) + exp2_(x1 - m) + exp2_(x2 - m) + exp2_(x3 - m);
      s += __shfl_xor(s, 1);
      s += __shfl_xor(s, 2);
      s += __shfl_xor(s, 4);
      s += __shfl_xor(s, 8);
      F[r] = -4.0f - (m + log2_(s));
    }
    // g update: G_j = lb2_j - lse2_i(F_i - Cb_ij); reduce over r (local) + ig (xor 16,32)
    #pragma unroll
    for (int t = 0; t < 4; ++t) {
      float y0 = F[0] - Cb[0][t], y1 = F[1] - Cb[1][t];
      float y2 = F[2] - Cb[2][t], y3 = F[3] - Cb[3][t];
      float m = fmaxf(fmaxf(y0, y1), fmaxf(y2, y3));
      m = fmaxf(m, __shfl_xor(m, 16));
      m = fmaxf(m, __shfl_xor(m, 32));
      float s = exp2_(y0 - m) + exp2_(y1 - m) + exp2_(y2 - m) + exp2_(y3 - m);
      s += __shfl_xor(s, 16);
      s += __shfl_xor(s, 32);
      G[t] = lb2[t] - (m + log2_(s));
    }
  }

  // ---- dist = sum P*C = sum 2^(F+G-Cb) * Cb * (eps*ln2) ----
  float d = 0.f;
  #pragma unroll
  for (int r = 0; r < 4; ++r)
    #pragma unroll
    for (int t = 0; t < 4; ++t) {
      float e = exp2_(F[r] + G[t] - Cb[r][t]);
      d = fmaf(e, Cb[r][t], d);
    }
  d += __shfl_xor(d, 1);
  d += __shfl_xor(d, 2);
  d += __shfl_xor(d, 4);
  d += __shfl_xor(d, 8);
  d += __shfl_xor(d, 16);
  d += __shfl_xor(d, 32);

  if (lane == 0) {
    // mol = -dist_nat * 16 * n / 100 ; dist_nat = d * eps * ln2
    mol[pair] = -d * (EPS_ * LN2_ * 16.0f / 100.0f) * (float)n;
  }
}

__global__ __launch_bounds__(256) void ffn_head(
    const float* __restrict__ mol,  // [512][32]
    const float* __restrict__ W1,   // [32][256]
    const float* __restrict__ b1,   // [256]
    const float* __restrict__ W2,   // [256][1]
    const float* __restrict__ b2,   // [1]
    float*       __restrict__ out)  // [512]
{
  const int b = blockIdx.x;
  const int j = threadIdx.x;
  float m[32];
  #pragma unroll
  for (int k = 0; k < 32; ++k) m[k] = mol[b * 32 + k];
  float acc = b1[j];
  #pragma unroll
  for (int k = 0; k < 32; ++k) acc = fmaf(m[k], W1[k * 256 + j], acc);
  float v = fmaxf(acc, 0.0f) * W2[j];
  #pragma unroll
  for (int mask = 1; mask < 64; mask <<= 1) v += __shfl_xor(v, mask);
  __shared__ float red[4];
  if ((threadIdx.x & 63) == 0) red[threadIdx.x >> 6] = v;
  __syncthreads();
  if (threadIdx.x == 0) out[b] = red[0] + red[1] + red[2] + red[3] + b2[0];
}

extern "C" void kernel_launch(void* const* d_in, const int* in_sizes, int n_in,
                              void* d_out, int out_size, void* d_ws, size_t ws_size,
                              hipStream_t stream) {
  const float* atom_h = (const float*)d_in[0];
  const float* pc_X   = (const float*)d_in[1];
  const float* W1     = (const float*)d_in[2];
  const float* b1     = (const float*)d_in[3];
  const float* W2     = (const float*)d_in[4];
  const float* b2     = (const float*)d_in[5];
  const int*   n_at   = (const int*)d_in[6];

  float* mol = (float*)d_ws;           // 512*32*4 = 64 KB scratch
  float* out = (float*)d_out;          // [512] fp32

  sink_fused<<<4096, 256, 0, stream>>>(atom_h, pc_X, n_at, mol);
  ffn_head<<<512, 256, 0, stream>>>(mol, W1, b1, W2, b2, out);
}

// Round 2
// 187.921 us; speedup vs baseline: 1.6214x; 1.6214x over previous
//
#include <hip/hip_runtime.h>

// ProtoNet forward: per (b,p) pair 16x64 sinkhorn (30 it, eps=0.1) + FFN head.
// Layout: one wave per pair. lane = ig*16 + jg (ig=0..3, jg=0..15).
// Lane owns rows i = ig + 4r (r=0..3) and cols j = jg + 16t (t=0..3).
// Iterations 1-2: log-domain (base-2). Iterations 3-30: stabilized
// multiplicative domain on E = 2^(F+G-Cb) (entries <= 1/8 after a full
// log iteration since col sums = b_j exactly), re-absorbing u,v into E
// every 7 iterations to bound drift and keep fp32 precision.

constexpr int   LMAX_ = 64, D_ = 128, PCS_ = 16;
constexpr float EPS_   = 0.1f;
constexpr float LOG2E_ = 1.4426950408889634f;
constexpr float SCALE_ = LOG2E_ / EPS_;          // C -> base-2/eps units
constexpr float LN2_   = 0.6931471805599453f;
constexpr int   LDSW_  = 132;                    // odd*4 stride: 2-way-only LDS conflicts

#if __has_builtin(__builtin_amdgcn_exp2f)
__device__ __forceinline__ float exp2_(float x) { return __builtin_amdgcn_exp2f(x); }
#else
__device__ __forceinline__ float exp2_(float x) { return exp2f(x); }
#endif
#if __has_builtin(__builtin_amdgcn_log2f)
__device__ __forceinline__ float log2_(float x) { return __builtin_amdgcn_log2f(x); }
#elif __has_builtin(__builtin_amdgcn_logf)
__device__ __forceinline__ float log2_(float x) { return __builtin_amdgcn_logf(x); }  // v_log_f32 = log2
#else
__device__ __forceinline__ float log2_(float x) { return log2f(x); }
#endif
#if __has_builtin(__builtin_amdgcn_rcpf)
__device__ __forceinline__ float rcp_(float x) { return __builtin_amdgcn_rcpf(x); }
#else
__device__ __forceinline__ float rcp_(float x) { return 1.0f / x; }
#endif

__global__ __launch_bounds__(256, 4) void sink_fused(
    const float* __restrict__ atom_h,   // [512][64][128]
    const float* __restrict__ pc_X,     // [32][16][128]
    const int*   __restrict__ n_atoms,  // [512]
    float*       __restrict__ mol)      // [512][32] (ws)
{
  __shared__ float Alds[64 * LDSW_];

  const int b    = blockIdx.x >> 3;                 // 8 blocks per molecule
  const int wave = threadIdx.x >> 6;
  const int pair = blockIdx.x * 4 + wave;           // = b*32 + p
  const int p    = pair & 31;
  const int lane = threadIdx.x & 63;
  const int ig   = lane >> 4;
  const int jg   = lane & 15;

  // ---- stage atom_h[b] into LDS (coalesced), padded stride ----
  const float* Ag = atom_h + (size_t)b * (LMAX_ * D_);
  #pragma unroll
  for (int u = 0; u < 8; ++u) {
    int fidx = u * 256 + threadIdx.x;               // float4 index, 2048 total
    int row  = fidx >> 5;
    int c4   = fidx & 31;
    float4 v = *reinterpret_cast<const float4*>(Ag + row * D_ + c4 * 4);
    *reinterpret_cast<float4*>(&Alds[row * LDSW_ + c4 * 4]) = v;
  }
  __syncthreads();

  const int    n  = n_atoms[b];
  const float* Xg = pc_X + (size_t)p * (PCS_ * D_);

  // ---- cost tile: Cb[r][t] = SCALE * (||x_i||^2 + ||a_j||^2 - 2 x_i.a_j) ----
  float acc[4][4], an[4], pn[4];
  #pragma unroll
  for (int r = 0; r < 4; ++r) { pn[r] = 0.f;
    #pragma unroll
    for (int t = 0; t < 4; ++t) acc[r][t] = 0.f; }
  #pragma unroll
  for (int t = 0; t < 4; ++t) an[t] = 0.f;

  for (int c = 0; c < 32; ++c) {
    float4 at[4], px[4];
    #pragma unroll
    for (int t = 0; t < 4; ++t)
      at[t] = *reinterpret_cast<const float4*>(&Alds[(jg + 16 * t) * LDSW_ + c * 4]);
    #pragma unroll
    for (int r = 0; r < 4; ++r)
      px[r] = *reinterpret_cast<const float4*>(Xg + (ig + 4 * r) * D_ + c * 4);
    #pragma unroll
    for (int r = 0; r < 4; ++r)
      #pragma unroll
      for (int t = 0; t < 4; ++t) {
        acc[r][t] = fmaf(px[r].x, at[t].x, acc[r][t]);
        acc[r][t] = fmaf(px[r].y, at[t].y, acc[r][t]);
        acc[r][t] = fmaf(px[r].z, at[t].z, acc[r][t]);
        acc[r][t] = fmaf(px[r].w, at[t].w, acc[r][t]);
      }
    #pragma unroll
    for (int t = 0; t < 4; ++t) {
      an[t] = fmaf(at[t].x, at[t].x, an[t]); an[t] = fmaf(at[t].y, at[t].y, an[t]);
      an[t] = fmaf(at[t].z, at[t].z, an[t]); an[t] = fmaf(at[t].w, at[t].w, an[t]);
    }
    #pragma unroll
    for (int r = 0; r < 4; ++r) {
      pn[r] = fmaf(px[r].x, px[r].x, pn[r]); pn[r] = fmaf(px[r].y, px[r].y, pn[r]);
      pn[r] = fmaf(px[r].z, px[r].z, pn[r]); pn[r] = fmaf(px[r].w, px[r].w, pn[r]);
    }
  }

  float Cb[4][4];
  #pragma unroll
  for (int r = 0; r < 4; ++r)
    #pragma unroll
    for (int t = 0; t < 4; ++t)
      Cb[r][t] = fmaf(-2.0f, acc[r][t], pn[r] + an[t]) * SCALE_;

  // ---- phase 1: 2 log-domain iterations (base-2 units) ----
  float lb2[4], G[4], F[4];
  const float lbv = -log2_((float)n);
  bool jv[4];
  #pragma unroll
  for (int t = 0; t < 4; ++t) {
    const int j = jg + 16 * t;
    jv[t]  = (j < n);
    lb2[t] = jv[t] ? lbv : -1.4426950e9f;    // log2e * NEG
    G[t]   = jv[t] ? 0.0f : -1e9f;           // padded cols contribute exactly 0 from it 1
  }

  for (int it = 0; it < 2; ++it) {
    #pragma unroll
    for (int r = 0; r < 4; ++r) {
      float x0 = G[0] - Cb[r][0], x1 = G[1] - Cb[r][1];
      float x2 = G[2] - Cb[r][2], x3 = G[3] - Cb[r][3];
      float m = fmaxf(fmaxf(x0, x1), fmaxf(x2, x3));
      m = fmaxf(m, __shfl_xor(m, 1));
      m = fmaxf(m, __shfl_xor(m, 2));
      m = fmaxf(m, __shfl_xor(m, 4));
      m = fmaxf(m, __shfl_xor(m, 8));
      float s = exp2_(x0 - m) + exp2_(x1 - m) + exp2_(x2 - m) + exp2_(x3 - m);
      s += __shfl_xor(s, 1);
      s += __shfl_xor(s, 2);
      s += __shfl_xor(s, 4);
      s += __shfl_xor(s, 8);
      F[r] = -4.0f - (m + log2_(s));
    }
    #pragma unroll
    for (int t = 0; t < 4; ++t) {
      float y0 = F[0] - Cb[0][t], y1 = F[1] - Cb[1][t];
      float y2 = F[2] - Cb[2][t], y3 = F[3] - Cb[3][t];
      float m = fmaxf(fmaxf(y0, y1), fmaxf(y2, y3));
      m = fmaxf(m, __shfl_xor(m, 16));
      m = fmaxf(m, __shfl_xor(m, 32));
      float s = exp2_(y0 - m) + exp2_(y1 - m) + exp2_(y2 - m) + exp2_(y3 - m);
      s += __shfl_xor(s, 16);
      s += __shfl_xor(s, 32);
      G[t] = lb2[t] - (m + log2_(s));
    }
  }

  // ---- phase 2: 28 multiplicative iterations on E = 2^(F+G-Cb) ----
  // After a g-update, col sums of E are exactly b_j => entries <= 1/8.
  float E[4][4];
  #pragma unroll
  for (int r = 0; r < 4; ++r)
    #pragma unroll
    for (int t = 0; t < 4; ++t)
      E[r][t] = exp2_(F[r] + G[t] - Cb[r][t]);   // padded col -> exactly 0

  const float bn = 1.0f / (float)n;
  float u[4], v[4];

  #pragma unroll 1
  for (int blk = 0; blk < 4; ++blk) {            // 4 blocks x 7 iters = 28
    #pragma unroll 1
    for (int it = 0; it < 7; ++it) {
      // u_i = (1/16) / sum_j E_ij v_j   (first it of blk: v == 1)
      #pragma unroll
      for (int r = 0; r < 4; ++r) {
        float s;
        if (it == 0 && true) {
          s = E[r][0] + E[r][1] + E[r][2] + E[r][3];
        } else {
          s = E[r][0] * v[0];
          s = fmaf(E[r][1], v[1], s);
          s = fmaf(E[r][2], v[2], s);
          s = fmaf(E[r][3], v[3], s);
        }
        s += __shfl_xor(s, 1);
        s += __shfl_xor(s, 2);
        s += __shfl_xor(s, 4);
        s += __shfl_xor(s, 8);
        u[r] = 0.0625f * rcp_(s);
      }
      // v_j = (1/n) / sum_i E_ij u_i ; padded col stays 0
      #pragma unroll
      for (int t = 0; t < 4; ++t) {
        float s = E[0][t] * u[0];
        s = fmaf(E[1][t], u[1], s);
        s = fmaf(E[2][t], u[2], s);
        s = fmaf(E[3][t], u[3], s);
        s += __shfl_xor(s, 16);
        s += __shfl_xor(s, 32);
        v[t] = jv[t] ? (bn * rcp_(s)) : 0.0f;
      }
    }
    // re-absorb u,v into E; resets u=v=1 for next block
    #pragma unroll
    for (int r = 0; r < 4; ++r) {
      #pragma unroll
      for (int t = 0; t < 4; ++t)
        E[r][t] *= u[r] * v[t];
    }
  }

  // ---- dist: after final absorb E == P. d = sum E*Cb (base-2 units) ----
  float d = 0.f;
  #pragma unroll
  for (int r = 0; r < 4; ++r)
    #pragma unroll
    for (int t = 0; t < 4; ++t)
      d = fmaf(E[r][t], Cb[r][t], d);
  d += __shfl_xor(d, 1);
  d += __shfl_xor(d, 2);
  d += __shfl_xor(d, 4);
  d += __shfl_xor(d, 8);
  d += __shfl_xor(d, 16);
  d += __shfl_xor(d, 32);

  if (lane == 0) {
    // mol = -dist_nat * 16 * n / 100 ; dist_nat = d * eps * ln2 (Cb units -> nats)
    mol[pair] = -d * (EPS_ * LN2_ * 16.0f / 100.0f) * (float)n;
  }
}

__global__ __launch_bounds__(256) void ffn_head(
    const float* __restrict__ mol,  // [512][32]
    const float* __restrict__ W1,   // [32][256]
    const float* __restrict__ b1,   // [256]
    const float* __restrict__ W2,   // [256][1]
    const float* __restrict__ b2,   // [1]
    float*       __restrict__ out)  // [512]
{
  const int b = blockIdx.x;
  const int j = threadIdx.x;
  float m[32];
  #pragma unroll
  for (int k = 0; k < 32; ++k) m[k] = mol[b * 32 + k];
  float acc = b1[j];
  #pragma unroll
  for (int k = 0; k < 32; ++k) acc = fmaf(m[k], W1[k * 256 + j], acc);
  float v = fmaxf(acc, 0.0f) * W2[j];
  #pragma unroll
  for (int mask = 1; mask < 64; mask <<= 1) v += __shfl_xor(v, mask);
  __shared__ float red[4];
  if ((threadIdx.x & 63) == 0) red[threadIdx.x >> 6] = v;
  __syncthreads();
  if (threadIdx.x == 0) out[b] = red[0] + red[1] + red[2] + red[3] + b2[0];
}

extern "C" void kernel_launch(void* const* d_in, const int* in_sizes, int n_in,
                              void* d_out, int out_size, void* d_ws, size_t ws_size,
                              hipStream_t stream) {
  const float* atom_h = (const float*)d_in[0];
  const float* pc_X   = (const float*)d_in[1];
  const float* W1     = (const float*)d_in[2];
  const float* b1     = (const float*)d_in[3];
  const float* W2     = (const float*)d_in[4];
  const float* b2     = (const float*)d_in[5];
  const int*   n_at   = (const int*)d_in[6];

  float* mol = (float*)d_ws;           // 512*32*4 = 64 KB scratch
  float* out = (float*)d_out;          // [512] fp32

  sink_fused<<<4096, 256, 0, stream>>>(atom_h, pc_X, n_at, mol);
  ffn_head<<<512, 256, 0, stream>>>(mol, W1, b1, W2, b2, out);
}